// Round 1
// baseline (388.231 us; speedup 1.0000x reference)
//
#include <hip/hip_runtime.h>

// BagRE: segment-mean over sorted bags + linear classifier, fused.
//   hidden [N=262144, H=256] f32, W [C=128, H=256] f32, b [C] f32,
//   bag_id [N] i32 (sorted)  ->  out [NUM_BAGS=8192, C=128] f32
//
// Memory-bound: 256 MB hidden read dominates (~41 us floor @ 6.3 TB/s).
// One fused kernel: 1024 blocks x 256 threads, 8 bags/block.

#define NBAGS 8192
#define HDIM 256
#define CDIM 128
#define BPB 8  // bags per block

__global__ __launch_bounds__(256) void bagre_kernel(
    const float* __restrict__ hidden,
    const float* __restrict__ W,
    const float* __restrict__ b,
    const int* __restrict__ bag_id,
    float* __restrict__ out,
    int N)
{
    __shared__ __align__(16) float s_mean[BPB][HDIM];   // 8 KB
    __shared__ __align__(16) float s_acc[4][HDIM];      // 4 KB
    __shared__ float s_part[2][BPB][CDIM];              // 8 KB
    __shared__ int s_bound[BPB + 1];

    const int t  = threadIdx.x;
    const int g0 = blockIdx.x * BPB;

    // --- segment boundaries: bag_id is sorted; lower_bound(g0 + j) ---
    if (t <= BPB) {
        const int target = g0 + t;
        int lo = 0, hi = N;
        while (lo < hi) {
            const int mid = (lo + hi) >> 1;
            if (bag_id[mid] < target) lo = mid + 1; else hi = mid;
        }
        s_bound[t] = lo;
    }
    __syncthreads();

    // --- phase 1: per-bag mean into s_mean ---
    // wave q (t>>6) takes rows s+q, s+q+4, ...; lane holds 4 consecutive cols.
    const int q    = t >> 6;
    const int lane = t & 63;
    const int col4 = lane << 2;

    for (int j = 0; j < BPB; ++j) {
        const int s = s_bound[j];
        const int e = s_bound[j + 1];
        float4 acc = make_float4(0.f, 0.f, 0.f, 0.f);
        for (int r = s + q; r < e; r += 4) {  // trip count wave-uniform
            const float4 v = *(const float4*)(hidden + (size_t)r * HDIM + col4);
            acc.x += v.x; acc.y += v.y; acc.z += v.z; acc.w += v.w;
        }
        *(float4*)(&s_acc[q][col4]) = acc;
        __syncthreads();
        const int cnt = e - s;
        const float inv = 1.0f / (float)(cnt > 1 ? cnt : 1);
        // thread t owns column h = t
        s_mean[j][t] = (s_acc[0][t] + s_acc[1][t] + s_acc[2][t] + s_acc[3][t]) * inv;
        __syncthreads();  // protect s_acc before next bag
    }

    // --- phase 2: logits = mean @ W^T + b, 8-bag register blocking ---
    // thread t: class c = t&127, K-half = t>>7. W value reused across 8 bags.
    const int c    = t & (CDIM - 1);
    const int half = t >> 7;
    const float* __restrict__ wrow = W + (size_t)c * HDIM + half * (HDIM / 2);

    float acc[BPB];
#pragma unroll
    for (int j = 0; j < BPB; ++j) acc[j] = 0.f;

    for (int hh = 0; hh < HDIM / 2; hh += 4) {
        const float4 wv = *(const float4*)(wrow + hh);
        const int hbase = half * (HDIM / 2) + hh;
#pragma unroll
        for (int j = 0; j < BPB; ++j) {
            // s_mean reads are wave-uniform -> LDS broadcast, conflict-free
            acc[j] += s_mean[j][hbase + 0] * wv.x
                    + s_mean[j][hbase + 1] * wv.y
                    + s_mean[j][hbase + 2] * wv.z
                    + s_mean[j][hbase + 3] * wv.w;
        }
    }

#pragma unroll
    for (int j = 0; j < BPB; ++j) s_part[half][j][c] = acc[j];
    __syncthreads();

    for (int idx = t; idx < BPB * CDIM; idx += 256) {
        const int j  = idx >> 7;
        const int cc = idx & (CDIM - 1);
        out[(size_t)(g0 + j) * CDIM + cc] =
            s_part[0][j][cc] + s_part[1][j][cc] + b[cc];
    }
}

extern "C" void kernel_launch(void* const* d_in, const int* in_sizes, int n_in,
                              void* d_out, int out_size, void* d_ws, size_t ws_size,
                              hipStream_t stream) {
    const float* hidden = (const float*)d_in[0];
    const float* W      = (const float*)d_in[1];
    const float* b      = (const float*)d_in[2];
    const int*   bag_id = (const int*)d_in[3];
    float* out = (float*)d_out;
    const int N = in_sizes[3];  // 262144

    bagre_kernel<<<NBAGS / BPB, 256, 0, stream>>>(hidden, W, b, bag_id, out, N);
}

// Round 2
// 387.493 us; speedup vs baseline: 1.0019x; 1.0019x over previous
//
#include <hip/hip_runtime.h>

// BagRE: segment-mean over sorted bags + linear classifier, fused.
//   hidden [N=262144, H=256] f32, W [C=128, H=256] f32, b [C] f32,
//   bag_id [N] i32 (sorted)  ->  out [NUM_BAGS=8192, C=128] f32
//
// Memory-bound: 256 MB hidden read dominates (~42 us floor @ 6.3 TB/s).
// R1 lesson: per-bag cross-wave reduction cost 16 barriers/block -> each
// barrier drains vmcnt -> latency-bound at 675 GB/s. Fix: one wave owns
// whole bags (2 each), registers accumulate across rows, phase 1 has ONE
// barrier. 4-row unroll keeps ~4 KB/wave of loads in flight.

#define NBAGS 8192
#define HDIM 256
#define CDIM 128
#define BPB 8  // bags per block

__global__ __launch_bounds__(256) void bagre_kernel(
    const float* __restrict__ hidden,
    const float* __restrict__ W,
    const float* __restrict__ b,
    const int* __restrict__ bag_id,
    float* __restrict__ out,
    int N)
{
    __shared__ __align__(16) float s_mean[BPB][HDIM];   // 8 KB
    __shared__ float s_part[2][BPB][CDIM];              // 8 KB
    __shared__ int s_bound[BPB + 1];

    const int t  = threadIdx.x;
    const int g0 = blockIdx.x * BPB;

    // --- segment boundaries: bag_id is sorted; lower_bound(g0 + t) ---
    if (t <= BPB) {
        const int target = g0 + t;
        int lo = 0, hi = N;
        while (lo < hi) {
            const int mid = (lo + hi) >> 1;
            if (bag_id[mid] < target) lo = mid + 1; else hi = mid;
        }
        s_bound[t] = lo;
    }
    __syncthreads();

    // --- phase 1: wave q owns bags 2q and 2q+1; no cross-wave reduce ---
    // lane holds 4 consecutive cols (64 lanes x float4 = full 256-col row,
    // each row load = one contiguous 1 KB wave transaction).
    const int q    = t >> 6;
    const int lane = t & 63;
    const int col4 = lane << 2;

#pragma unroll
    for (int jj = 0; jj < 2; ++jj) {
        const int j = q * 2 + jj;
        const int s = s_bound[j];
        const int e = s_bound[j + 1];

        float4 a0 = make_float4(0.f, 0.f, 0.f, 0.f);
        float4 a1 = a0, a2 = a0, a3 = a0;

        const float* __restrict__ p = hidden + (size_t)s * HDIM + col4;
        int r = s;
        for (; r + 4 <= e; r += 4, p += 4 * HDIM) {
            // 4 independent 16 B loads -> 4 KB/wave in flight
            const float4 v0 = *(const float4*)(p + 0 * HDIM);
            const float4 v1 = *(const float4*)(p + 1 * HDIM);
            const float4 v2 = *(const float4*)(p + 2 * HDIM);
            const float4 v3 = *(const float4*)(p + 3 * HDIM);
            a0.x += v0.x; a0.y += v0.y; a0.z += v0.z; a0.w += v0.w;
            a1.x += v1.x; a1.y += v1.y; a1.z += v1.z; a1.w += v1.w;
            a2.x += v2.x; a2.y += v2.y; a2.z += v2.z; a2.w += v2.w;
            a3.x += v3.x; a3.y += v3.y; a3.z += v3.z; a3.w += v3.w;
        }
        for (; r < e; ++r, p += HDIM) {
            const float4 v0 = *(const float4*)p;
            a0.x += v0.x; a0.y += v0.y; a0.z += v0.z; a0.w += v0.w;
        }

        const int cnt = e - s;
        const float inv = 1.0f / (float)(cnt > 1 ? cnt : 1);
        float4 m;
        m.x = (a0.x + a1.x + a2.x + a3.x) * inv;
        m.y = (a0.y + a1.y + a2.y + a3.y) * inv;
        m.z = (a0.z + a1.z + a2.z + a3.z) * inv;
        m.w = (a0.w + a1.w + a2.w + a3.w) * inv;
        *(float4*)(&s_mean[j][col4]) = m;
    }
    __syncthreads();  // the ONLY phase-1 barrier

    // --- phase 2: logits = mean @ W^T + b, 8-bag register blocking ---
    // thread t: class c = t&127, K-half = t>>7. W value reused across 8 bags.
    // hbase is wave-uniform -> s_mean reads are LDS broadcasts (free).
    const int c    = t & (CDIM - 1);
    const int half = t >> 7;
    const float* __restrict__ wrow = W + (size_t)c * HDIM + half * (HDIM / 2);

    float acc[BPB];
#pragma unroll
    for (int j = 0; j < BPB; ++j) acc[j] = 0.f;

    for (int hh = 0; hh < HDIM / 2; hh += 4) {
        const float4 wv = *(const float4*)(wrow + hh);
        const int hbase = half * (HDIM / 2) + hh;
#pragma unroll
        for (int j = 0; j < BPB; ++j) {
            acc[j] += s_mean[j][hbase + 0] * wv.x
                    + s_mean[j][hbase + 1] * wv.y
                    + s_mean[j][hbase + 2] * wv.z
                    + s_mean[j][hbase + 3] * wv.w;
        }
    }

#pragma unroll
    for (int j = 0; j < BPB; ++j) s_part[half][j][c] = acc[j];
    __syncthreads();

    for (int idx = t; idx < BPB * CDIM; idx += 256) {
        const int j  = idx >> 7;
        const int cc = idx & (CDIM - 1);
        out[(size_t)(g0 + j) * CDIM + cc] =
            s_part[0][j][cc] + s_part[1][j][cc] + b[cc];
    }
}

extern "C" void kernel_launch(void* const* d_in, const int* in_sizes, int n_in,
                              void* d_out, int out_size, void* d_ws, size_t ws_size,
                              hipStream_t stream) {
    const float* hidden = (const float*)d_in[0];
    const float* W      = (const float*)d_in[1];
    const float* b      = (const float*)d_in[2];
    const int*   bag_id = (const int*)d_in[3];
    float* out = (float*)d_out;
    const int N = in_sizes[3];  // 262144

    bagre_kernel<<<NBAGS / BPB, 256, 0, stream>>>(hidden, W, b, bag_id, out, N);
}